// Round 8
// baseline (123.634 us; speedup 1.0000x reference)
//
#include <hip/hip_runtime.h>

// EvalEig round 15: occupancy via LDS, not via caps. r14 split regressed
// (95 vs 85) -> revert to r12 monolith. r9 re-read: solve uses only 40 VGPR
// (r11 counter), so the (512,8) regression was SCHEDULING under a 64-reg
// ceiling (can't pipeline the 7 float4 table loads), not spills. This round:
// kCPB 16->8, block 512->256 -> LDS 36.8->21.6KB -> 7 blocks/CU = 7 waves/
// SIMD (was 4.4). Solve is latency-bound (VALU 27%, HBM 13%, occ 55%):
// phase-3 is a 4-deep dependent-fma recurrence; more waves = TLP to hide it
// and the post-fill store backpressure. No structural change otherwise.

namespace {
constexpr int kNE    = 4096;
constexpr int kNCH   = kNE * 3;        // 12288 chains
constexpr int kMatch = 100;
constexpr float kC   = 3.0f / 40.0f * 0.01f;
constexpr float kK1  = 13.0f / 15.0f * 0.01f;
constexpr float kK2  = 7.0f / 60.0f * 0.01f;
constexpr int kSeg        = 32;           // segments per chain
constexpr int kCPB        = 8;            // chains per block
constexpr int kBlk        = kCPB * kSeg;  // 256 threads
constexpr int kZeroBlocks = kNCH / kBlk;  // 48
constexpr int kInfBlocks  = kNCH / kCPB;  // 1536
}

__device__ __forceinline__ float rcp_f(float x) { return __builtin_amdgcn_rcpf(x); }
__device__ __forceinline__ float rcp_nr(float x) {
    float r = __builtin_amdgcn_rcpf(x);
    return fmaf(fmaf(-x, r, 1.0f), r, r);
}
__device__ __forceinline__ void nt_store(float* p, float v) {
    __builtin_nontemporal_store(v, p);
}

__global__ __launch_bounds__(256, 4) void solve_kernel(const float* __restrict__ energy,
                                                       float* __restrict__ out,
                                                       float* __restrict__ ws)
{
    // gtp[k] = 1/(100 - 0.1*(k-3)) for k in [4,901]; 1.0 dummies elsewhere.
    // +3 shift -> every 4-step group read is one aligned ds_read_b128.
    __shared__ __align__(16) float gtp[908];          // 3.6 KB
    __shared__ float sM[kSeg][4][kCPB][4];            // 16 KB transfer matrices
    __shared__ float2 sRed[kSeg][kCPB];               // 2 KB integral partials

    const int bid = (int)blockIdx.x;
    const int tid = (int)threadIdx.x;
    float* uzero = out + kNCH;
    float* uinf  = out + kNCH + (size_t)kMatch * kNCH;

    if (bid < kZeroBlocks) {
        // ---------------- u_zero: outward solve, 94 steps, 1 thread/chain ----
        const int t  = bid * kBlk + tid;
        const int l  = t % 3;
        const int ei = t / 3;
        const float e = energy[ei], negE = -e;
        const float ll1 = (float)(l * (l + 1));
        const float rdiv = (l == 0) ? 0.5f : ((l == 1) ? 0.25f : (1.0f/6.0f));
        float p0,p1,p2,p3,p4;
        {
            float pw[5];
            #pragma unroll
            for (int k = 0; k < 5; ++k) {
                float r = 0.1f * (float)(k + 1);
                float rl1 = (l == 0) ? r : ((l == 1) ? r*r : r*r*r);
                pw[k] = rl1 - (rl1 * r) * rdiv;
                nt_store(&uzero[(size_t)k * kNCH + t], pw[k]);
            }
            nt_store(&uzero[(size_t)5 * kNCH + t], pw[4]);
            p0=pw[0]; p1=pw[1]; p2=pw[2]; p3=pw[3]; p4=pw[4];
        }
        float acc4, acc2;
        {
            float q0=p0*p0, q1=p1*p1, q2=p2*p2, q3=p3*p3, q4=p4*p4;
            acc4 = 7.0f*q0*q0 + 32.0f*q1*q1 + 32.0f*q3*q3 + 14.0f*q4*q4 + 32.0f*q4*q4;
            acc2 = q2;
        }
        float f0, f1, f2, f3;
        {
            float i1 = rcp_f(0.2f), i2 = rcp_f(0.3f), i3 = rcp_f(0.4f), i4 = rcp_f(0.5f);
            f0 = fmaf(i1, fmaf(ll1, i1, -1.0f), negE);
            f1 = fmaf(i2, fmaf(ll1, i2, -1.0f), negE);
            f2 = fmaf(i3, fmaf(ll1, i3, -1.0f), negE);
            f3 = fmaf(i4, fmaf(ll1, i4, -1.0f), negE);
        }
        float* ptr = uzero + (size_t)6 * kNCH + t;
        #pragma unroll 4
        for (int j = 5; j <= 98; ++j) {
            float ri = rcp_f(fmaf((float)j, 0.1f, 0.1f));
            float f4 = fmaf(ri, fmaf(ll1, ri, -1.0f), negE);
            float iv = rcp_f(fmaf(-kC, f4, 1.0f));
            float a  = fmaf(kC  * f0, iv, -1.0f);
            float b  = fmaf(kK1 * f1, iv,  2.0f);
            float cc = fmaf(kK2 * f2, iv, -2.0f);
            float d  = fmaf(kK1 * f3, iv,  2.0f);
            float nw = fmaf(d, p4, fmaf(cc, p3, fmaf(b, p2, a * p1)));
            nt_store(ptr, nw); ptr += kNCH;
            float v2 = nw*nw, v4 = v2*v2;
            if (j <= 94) {
                int m = (j + 1) & 3;
                if (m == 2)      acc2 += v2;
                else if (m == 0) acc4 += 14.0f * v4;
                else             acc4 += 32.0f * v4;
            } else if (j == 95) {
                acc4 += 7.0f * v4;
            }
            f0 = f1; f1 = f2; f2 = f3; f3 = f4;
            p0 = p1; p1 = p2; p2 = p3; p3 = p4; p4 = nw;
        }
        float integ = fmaf(12.0f, acc2, acc4) * (2.0f * 0.1f / 45.0f);
        float deriv = fmaf(25.0f, p4, fmaf(-48.0f, p3, fmaf(36.0f, p2,
                      fmaf(-16.0f, p1, 3.0f * p0)))) * (1.0f / 1.2f);
        ws[2 * kNCH + t] = deriv / p4;
        ws[3 * kNCH + t] = integ / (p4 * p4);
        return;
    }

    // ---------------- u_infty: 32-segment inward solve ----------------
    for (int k = tid; k < 908; k += kBlk) {
        int j = k - 3;
        gtp[k] = (j >= 1 && j <= 898) ? rcp_nr(fmaf((float)j, -0.1f, 100.0f)) : 1.0f;
    }
    __syncthreads();

    const int b = bid - kZeroBlocks;
    const int g = tid & (kCPB - 1);        // chain within block 0..7
    const int s = tid >> 3;                // segment 0..31 (8 per wave)
    const int t = b * kCPB + g;
    const int l  = t % 3;
    const int ei = t / 3;
    const float e = energy[ei], negE = -e;
    const float ll1 = (float)(l * (l + 1));
    const int jstart = 5 + 28 * s;         // uniform; s31 has 2 dummy steps

    const float4* gq = (const float4*)(&gtp[jstart + 3]);
    float ff0, ff1, ff2, ff3;
    {
        const float4 wF = *(const float4*)(&gtp[jstart - 1]);  // j-4..j-1
        ff0 = fmaf(wF.x, fmaf(ll1, wF.x, -1.0f), negE);
        ff1 = fmaf(wF.y, fmaf(ll1, wF.y, -1.0f), negE);
        ff2 = fmaf(wF.z, fmaf(ll1, wF.z, -1.0f), negE);
        ff3 = fmaf(wF.w, fmaf(ll1, wF.w, -1.0f), negE);
    }
    float F0 = ff0, F1 = ff1, F2 = ff2, F3 = ff3;

    float ca, cb, cc_, cd;
#define COEF(RI, FA,FB,FC,FD) \
    { float f4 = fmaf(RI, fmaf(ll1, RI, -1.0f), negE); \
      float x  = kC * f4; \
      float iv = fmaf(x, x, x) + 1.0f; \
      ca  = fmaf(kC  * FA, iv, -1.0f); \
      cb  = fmaf(kK1 * FB, iv,  2.0f); \
      cc_ = fmaf(kK2 * FC, iv, -2.0f); \
      cd  = fmaf(kK1 * FD, iv,  2.0f); \
      FA = f4; }

#define MSTEP(RI, FA,FB,FC,FD, RA,RB,RC,RD) \
    { COEF(RI, FA,FB,FC,FD) \
      RA[0] = fmaf(cd,RD[0], fmaf(cc_,RC[0], fmaf(cb,RB[0], ca*RA[0]))); \
      RA[1] = fmaf(cd,RD[1], fmaf(cc_,RC[1], fmaf(cb,RB[1], ca*RA[1]))); \
      RA[2] = fmaf(cd,RD[2], fmaf(cc_,RC[2], fmaf(cb,RB[2], ca*RA[2]))); \
      RA[3] = fmaf(cd,RD[3], fmaf(cc_,RC[3], fmaf(cb,RB[3], ca*RA[3]))); }

    // ---- phase 1: companion products, uniform 28 steps for s<=30 ----
    if (s != 31) {
        float ra[4] = {1,0,0,0}, rb[4] = {0,1,0,0}, rc[4] = {0,0,1,0}, rd[4] = {0,0,0,1};
        #pragma unroll
        for (int gi = 0; gi < 7; ++gi) {
            const float4 w = gq[gi];
            MSTEP(w.x, F0,F1,F2,F3, ra,rb,rc,rd)
            MSTEP(w.y, F1,F2,F3,F0, rb,rc,rd,ra)
            MSTEP(w.z, F2,F3,F0,F1, rc,rd,ra,rb)
            MSTEP(w.w, F3,F0,F1,F2, rd,ra,rb,rc)
        }
        *(float4*)&sM[s][0][g][0] = make_float4(ra[0], ra[1], ra[2], ra[3]);
        *(float4*)&sM[s][1][g][0] = make_float4(rb[0], rb[1], rb[2], rb[3]);
        *(float4*)&sM[s][2][g][0] = make_float4(rc[0], rc[1], rc[2], rc[3]);
        *(float4*)&sM[s][3][g][0] = make_float4(rd[0], rd[1], rd[2], rd[3]);
    }
    __syncthreads();

    // ---- phase 2: per-chain serial combine (lanes tid 0..7). Reads each
    // segment's matrix rows, then overwrites row 0 with that segment's start
    // state (read-before-write makes the alias safe).
    if (s == 0) {
        const float se  = sqrtf(fabsf(e));
        const float rfc = (l == 0) ? 1.0f : ((l == 1) ? (1.0f/3.0f) : (1.0f/15.0f));
        const float rt1 = (l == 0) ? (1.0f/3.0f) : ((l == 1) ? (1.0f/5.0f) : (1.0f/7.0f));
        const float rt2 = (l == 0) ? (1.0f/30.0f) : ((l == 1) ? (1.0f/70.0f) : (1.0f/126.0f));
        float pw[5];
        #pragma unroll
        for (int k = 0; k < 5; ++k) {
            float rinf = 99.6f + 0.1f * (float)k;
            float x  = rinf * se;
            float xl = (l == 0) ? 1.0f : ((l == 1) ? x : x * x);
            float h  = x * x * 0.5f;
            pw[k] = rinf * (xl * rfc * (1.0f + h * rt1 + (h * h) * rt2));
        }
        nt_store(&uinf[(size_t)899 * kNCH + t], pw[4]);
        float st0 = pw[1], st1 = pw[2], st2 = pw[3], st3 = pw[4];
        for (int ss = 0; ss < kSeg; ++ss) {
            if (ss < kSeg - 1) {
                float4 M0 = *(const float4*)&sM[ss][0][g][0];
                float4 M1 = *(const float4*)&sM[ss][1][g][0];
                float4 M2 = *(const float4*)&sM[ss][2][g][0];
                float4 M3 = *(const float4*)&sM[ss][3][g][0];
                *(float4*)&sM[ss][0][g][0] = make_float4(st0, st1, st2, st3);
                float n0 = fmaf(M0.w,st3, fmaf(M0.z,st2, fmaf(M0.y,st1, M0.x*st0)));
                float n1 = fmaf(M1.w,st3, fmaf(M1.z,st2, fmaf(M1.y,st1, M1.x*st0)));
                float n2 = fmaf(M2.w,st3, fmaf(M2.z,st2, fmaf(M2.y,st1, M2.x*st0)));
                float n3 = fmaf(M3.w,st3, fmaf(M3.z,st2, fmaf(M3.y,st1, M3.x*st0)));
                st0 = n0; st1 = n1; st2 = n2; st3 = n3;
            } else {
                *(float4*)&sM[ss][0][g][0] = make_float4(st0, st1, st2, st3);
            }
        }
    }
    __syncthreads();

    // ---- phase 3: uniform 28-step replay (s31: last 2 steps dummy) ----
    // slot K=0..3 <-> j === 1,2,3,0 mod 4: weights {acc2, 32u^4, 14u^4, 32u^4}
    float W0[4] = {0.0f, 32.0f, 14.0f, 32.0f};
    float V0[4] = {1.0f, 0.0f, 0.0f, 0.0f};
    float WR[4] = {0.0f, 32.0f, 14.0f, 32.0f};
    float VR[4] = {1.0f, 0.0f, 0.0f, 0.0f};
    if (s == 0) {   // rows 898,897 beyond integration; j=7 -> boundary weight 7
        W0[0]=0.0f; V0[0]=0.0f; W0[1]=0.0f; W0[2]=7.0f; W0[3]=32.0f;
    }

    F0 = ff0; F1 = ff1; F2 = ff2; F3 = ff3;
    float p0, p1, p2, p3;
    {
        float4 P = *(const float4*)&sM[s][0][g][0];
        p0 = P.x; p1 = P.y; p2 = P.z; p3 = P.w;
    }
    float acc4 = 0.0f, acc2 = 0.0f;
    float* ptr = uinf + (size_t)(903 - jstart) * kNCH + t;
#define RSTEPW(RI, FA,FB,FC,FD, PA,PB,PC,PD, W,V,K) \
    { COEF(RI, FA,FB,FC,FD) \
      float nw = fmaf(cd,PD, fmaf(cc_,PC, fmaf(cb,PB, ca*PA))); \
      PA = nw; nt_store(ptr, nw); ptr -= kNCH; \
      float v2 = nw*nw, v4 = v2*v2; \
      acc4 = fmaf(W[K], v4, acc4); \
      acc2 = fmaf(V[K], v2, acc2); }
#define PG(G, W, V) \
    { const float4 w = gq[G]; \
      RSTEPW(w.x, F0,F1,F2,F3, p0,p1,p2,p3, W,V,0) \
      RSTEPW(w.y, F1,F2,F3,F0, p1,p2,p3,p0, W,V,1) \
      RSTEPW(w.z, F2,F3,F0,F1, p2,p3,p0,p1, W,V,2) \
      RSTEPW(w.w, F3,F0,F1,F2, p3,p0,p1,p2, W,V,3) }

    PG(0, W0, V0)
    PG(1, WR, VR) PG(2, WR, VR) PG(3, WR, VR) PG(4, WR, VR) PG(5, WR, VR)
    // rotation restored: p0..p3 = w[jstart+20..jstart+23]
    float h0 = p1, h1 = p2, h2 = p3;
    if (s == 31) { WR[2] = 0.0f; WR[3] = 0.0f; }   // j=899,900 dummies
    PG(6, WR, VR)
    float h3 = p0, h4 = p1;
#undef PG
#undef RSTEPW

    sRed[s][g] = make_float2(acc4, acc2);
    __syncthreads();

    if (s == kSeg - 1) {
        float a4 = 0.0f, a2 = 0.0f;
        #pragma unroll
        for (int ss = 0; ss < kSeg; ++ss) {
            float2 rr = sRed[ss][g];
            a4 += rr.x; a2 += rr.y;
        }
        // h0..h4 = w894..w898 -> u_infty rows 0..4
        nt_store(&uinf[(size_t)0 * kNCH + t], h0);
        nt_store(&uinf[(size_t)1 * kNCH + t], h1);
        nt_store(&uinf[(size_t)2 * kNCH + t], h2);
        nt_store(&uinf[(size_t)3 * kNCH + t], h3);
        nt_store(&uinf[(size_t)4 * kNCH + t], h4);
        float q0 = h0*h0, q1 = h1*h1, q2 = h2*h2, q3 = h3*h3, q4 = h4*h4;
        a4 += 7.0f*q0*q0 + 32.0f*q1*q1 + 32.0f*q3*q3 + 14.0f*q4*q4;
        a2 += q2;
        float integ = fmaf(12.0f, a2, a4) * (2.0f * 0.1f / 45.0f);
        float deriv = fmaf(25.0f, h0, fmaf(-48.0f, h1, fmaf(36.0f, h2,
                      fmaf(-16.0f, h3, 3.0f * h4)))) * (1.0f / 1.2f);
        ws[t]        = deriv / h0;            // lfunc_out (pre energy-reversal)
        ws[kNCH + t] = integ / (h0 * h0);     // integ_out / u_infty[0]^2
    }
#undef MSTEP
#undef COEF
}

__global__ __launch_bounds__(256) void final_kernel(const float* __restrict__ energy,
                                                    const float* __restrict__ ws,
                                                    float* __restrict__ out)
{
    int t = (int)blockIdx.x * 256 + (int)threadIdx.x;
    if (t >= kNCH) return;
    int l = t % 3, ei = t / 3;
    float lf_out = ws[(kNE - 1 - ei) * 3 + l];   // energy-axis reversed
    float lf_in  = ws[2 * kNCH + t];
    float den    = ws[kNCH + t] + ws[3 * kNCH + t];
    nt_store(&out[t], energy[ei] - (lf_out - lf_in) / den);
}

extern "C" void kernel_launch(void* const* d_in, const int* in_sizes, int n_in,
                              void* d_out, int out_size, void* d_ws, size_t ws_size,
                              hipStream_t stream) {
    (void)in_sizes; (void)n_in; (void)out_size; (void)ws_size;
    const float* energy = (const float*)d_in[0];
    float* out = (float*)d_out;
    float* ws  = (float*)d_ws;   // 4*12288 floats = 192 KB (in-bounds)
    solve_kernel<<<kZeroBlocks + kInfBlocks, 256, 0, stream>>>(energy, out, ws);
    final_kernel<<<kNCH / 256, 256, 0, stream>>>(energy, ws, out);
}

// Round 9
// 89.186 us; speedup vs baseline: 1.3863x; 1.3863x over previous
//
#include <hip/hip_runtime.h>

// EvalEig round 16: r15 regression diagnosed (32B/wave stores < 64B HBM atom
// -> masked partial writes, 0.74TB/s; kCPB must be >=16). Revert to the r10
// monolith (kCPB=16, 512thr, plain stores). New lever for the ~18us
// first-after-fill penalty: FIRST-TOUCH EVICTION. The 256MiB poison exactly
// fills Infinity Cache dirty; solve's 49MB of first-touch stores each evict
// poison to HBM, and those stalls serialize behind solve's latency-limited
// store issue. Fix: warm_kernel zero-fills all of `out` first at max MLP
// (pure store kernel ~8-12us does the eviction work at full port rate);
// solve then stores into resident dirty-ours lines at steady-state speed.
// Zeros are safe: solve+final overwrite every element of out.

namespace {
constexpr int kNE    = 4096;
constexpr int kNCH   = kNE * 3;        // 12288 chains
constexpr int kMatch = 100;
constexpr float kC   = 3.0f / 40.0f * 0.01f;
constexpr float kK1  = 13.0f / 15.0f * 0.01f;
constexpr float kK2  = 7.0f / 60.0f * 0.01f;
constexpr int kSeg        = 32;           // segments per chain
constexpr int kCPB        = 16;           // chains per block
constexpr int kZeroBlocks = kNCH / 512;   // 24
constexpr int kInfBlocks  = kNCH / kCPB;  // 768
}

__device__ __forceinline__ float rcp_f(float x) { return __builtin_amdgcn_rcpf(x); }
__device__ __forceinline__ float rcp_nr(float x) {
    float r = __builtin_amdgcn_rcpf(x);
    return fmaf(fmaf(-x, r, 1.0f), r, r);
}

// ---------------- warm: first-touch the whole out buffer at max MLP --------
__global__ __launch_bounds__(256) void warm_kernel(float4* __restrict__ out4, int n4)
{
    int stride = (int)gridDim.x * 256;
    float4 z = make_float4(0.f, 0.f, 0.f, 0.f);
    for (int i = (int)blockIdx.x * 256 + (int)threadIdx.x; i < n4; i += stride)
        out4[i] = z;
}

__global__ __launch_bounds__(512, 4) void solve_kernel(const float* __restrict__ energy,
                                                       float* __restrict__ out,
                                                       float* __restrict__ ws)
{
    // gtp[k] = 1/(100 - 0.1*(k-3)) for k in [4,901]; 1.0 dummies elsewhere.
    // +3 shift -> every 4-step group read is one aligned ds_read_b128.
    __shared__ __align__(16) float gtp[908];  // 3.6 KB
    __shared__ float sM[kSeg][4][kCPB][4];    // 32 KB: [seg][matrix row][chain][col]
    float* sF = &sM[0][0][0][0];

    const int bid = (int)blockIdx.x;
    const int tid = (int)threadIdx.x;
    float* uzero = out + kNCH;
    float* uinf  = out + kNCH + (size_t)kMatch * kNCH;

    if (bid < kZeroBlocks) {
        // ---------------- u_zero: outward solve, 94 steps, 1 thread/chain ----
        const int t  = bid * 512 + tid;
        const int l  = t % 3;
        const int ei = t / 3;
        const float e = energy[ei], negE = -e;
        const float ll1 = (float)(l * (l + 1));
        const float rdiv = (l == 0) ? 0.5f : ((l == 1) ? 0.25f : (1.0f/6.0f));
        float p0,p1,p2,p3,p4;
        {
            float pw[5];
            #pragma unroll
            for (int k = 0; k < 5; ++k) {
                float r = 0.1f * (float)(k + 1);
                float rl1 = (l == 0) ? r : ((l == 1) ? r*r : r*r*r);
                pw[k] = rl1 - (rl1 * r) * rdiv;
                uzero[(size_t)k * kNCH + t] = pw[k];
            }
            uzero[(size_t)5 * kNCH + t] = pw[4];
            p0=pw[0]; p1=pw[1]; p2=pw[2]; p3=pw[3]; p4=pw[4];
        }
        float acc4, acc2;
        {
            float q0=p0*p0, q1=p1*p1, q2=p2*p2, q3=p3*p3, q4=p4*p4;
            acc4 = 7.0f*q0*q0 + 32.0f*q1*q1 + 32.0f*q3*q3 + 14.0f*q4*q4 + 32.0f*q4*q4;
            acc2 = q2;
        }
        float f0, f1, f2, f3;
        {
            float i1 = rcp_f(0.2f), i2 = rcp_f(0.3f), i3 = rcp_f(0.4f), i4 = rcp_f(0.5f);
            f0 = fmaf(i1, fmaf(ll1, i1, -1.0f), negE);
            f1 = fmaf(i2, fmaf(ll1, i2, -1.0f), negE);
            f2 = fmaf(i3, fmaf(ll1, i3, -1.0f), negE);
            f3 = fmaf(i4, fmaf(ll1, i4, -1.0f), negE);
        }
        float* ptr = uzero + (size_t)6 * kNCH + t;
        #pragma unroll 4
        for (int j = 5; j <= 98; ++j) {
            float ri = rcp_f(fmaf((float)j, 0.1f, 0.1f));
            float f4 = fmaf(ri, fmaf(ll1, ri, -1.0f), negE);
            float iv = rcp_f(fmaf(-kC, f4, 1.0f));
            float a  = fmaf(kC  * f0, iv, -1.0f);
            float b  = fmaf(kK1 * f1, iv,  2.0f);
            float cc = fmaf(kK2 * f2, iv, -2.0f);
            float d  = fmaf(kK1 * f3, iv,  2.0f);
            float nw = fmaf(d, p4, fmaf(cc, p3, fmaf(b, p2, a * p1)));
            *ptr = nw; ptr += kNCH;
            float v2 = nw*nw, v4 = v2*v2;
            if (j <= 94) {
                int m = (j + 1) & 3;
                if (m == 2)      acc2 += v2;
                else if (m == 0) acc4 += 14.0f * v4;
                else             acc4 += 32.0f * v4;
            } else if (j == 95) {
                acc4 += 7.0f * v4;
            }
            f0 = f1; f1 = f2; f2 = f3; f3 = f4;
            p0 = p1; p1 = p2; p2 = p3; p3 = p4; p4 = nw;
        }
        float integ = fmaf(12.0f, acc2, acc4) * (2.0f * 0.1f / 45.0f);
        float deriv = fmaf(25.0f, p4, fmaf(-48.0f, p3, fmaf(36.0f, p2,
                      fmaf(-16.0f, p1, 3.0f * p0)))) * (1.0f / 1.2f);
        ws[2 * kNCH + t] = deriv / p4;
        ws[3 * kNCH + t] = integ / (p4 * p4);
        return;
    }

    // ---------------- u_infty: 32-segment inward solve ----------------
    for (int k = tid; k < 908; k += 512) {
        int j = k - 3;
        gtp[k] = (j >= 1 && j <= 898) ? rcp_nr(fmaf((float)j, -0.1f, 100.0f)) : 1.0f;
    }
    __syncthreads();

    const int b = bid - kZeroBlocks;
    const int g = tid & (kCPB - 1);        // chain within block
    const int s = tid >> 4;                // segment 0..31 (4 per wave)
    const int t = b * kCPB + g;
    const int l  = t % 3;
    const int ei = t / 3;
    const float e = energy[ei], negE = -e;
    const float ll1 = (float)(l * (l + 1));
    // uniform: seg s covers j = jstart .. jstart+27 (s31: last 2 are dummies)
    const int jstart = 5 + 28 * s;

    const float4* gq = (const float4*)(&gtp[jstart + 3]);   // group G = j jstart+4G..+3
    float ff0, ff1, ff2, ff3;
    {
        const float4 wF = *(const float4*)(&gtp[jstart - 1]);  // j-4..j-1
        ff0 = fmaf(wF.x, fmaf(ll1, wF.x, -1.0f), negE);
        ff1 = fmaf(wF.y, fmaf(ll1, wF.y, -1.0f), negE);
        ff2 = fmaf(wF.z, fmaf(ll1, wF.z, -1.0f), negE);
        ff3 = fmaf(wF.w, fmaf(ll1, wF.w, -1.0f), negE);
    }
    float F0 = ff0, F1 = ff1, F2 = ff2, F3 = ff3;

    float ca, cb, cc_, cd;
#define COEF(RI, FA,FB,FC,FD) \
    { float f4 = fmaf(RI, fmaf(ll1, RI, -1.0f), negE); \
      float x  = kC * f4; \
      float iv = fmaf(x, x, x) + 1.0f; \
      ca  = fmaf(kC  * FA, iv, -1.0f); \
      cb  = fmaf(kK1 * FB, iv,  2.0f); \
      cc_ = fmaf(kK2 * FC, iv, -2.0f); \
      cd  = fmaf(kK1 * FD, iv,  2.0f); \
      FA = f4; }

#define MSTEP(RI, FA,FB,FC,FD, RA,RB,RC,RD) \
    { COEF(RI, FA,FB,FC,FD) \
      RA[0] = fmaf(cd,RD[0], fmaf(cc_,RC[0], fmaf(cb,RB[0], ca*RA[0]))); \
      RA[1] = fmaf(cd,RD[1], fmaf(cc_,RC[1], fmaf(cb,RB[1], ca*RA[1]))); \
      RA[2] = fmaf(cd,RD[2], fmaf(cc_,RC[2], fmaf(cb,RB[2], ca*RA[2]))); \
      RA[3] = fmaf(cd,RD[3], fmaf(cc_,RC[3], fmaf(cb,RB[3], ca*RA[3]))); }

    // ---- phase 1: companion products, uniform 28 steps for s<=30 ----
    if (s != 31) {
        float ra[4] = {1,0,0,0}, rb[4] = {0,1,0,0}, rc[4] = {0,0,1,0}, rd[4] = {0,0,0,1};
        #pragma unroll
        for (int gi = 0; gi < 7; ++gi) {
            const float4 w = gq[gi];
            MSTEP(w.x, F0,F1,F2,F3, ra,rb,rc,rd)
            MSTEP(w.y, F1,F2,F3,F0, rb,rc,rd,ra)
            MSTEP(w.z, F2,F3,F0,F1, rc,rd,ra,rb)
            MSTEP(w.w, F3,F0,F1,F2, rd,ra,rb,rc)
        }
        *(float4*)&sM[s][0][g][0] = make_float4(ra[0], ra[1], ra[2], ra[3]);
        *(float4*)&sM[s][1][g][0] = make_float4(rb[0], rb[1], rb[2], rb[3]);
        *(float4*)&sM[s][2][g][0] = make_float4(rc[0], rc[1], rc[2], rc[3]);
        *(float4*)&sM[s][3][g][0] = make_float4(rd[0], rd[1], rd[2], rd[3]);
    }
    __syncthreads();

    // ---- phase 2: per-chain serial combine (lanes tid 0..15). Reads each
    // segment's matrix rows, then overwrites row 0 with that segment's start
    // state (read-before-write makes the alias safe).
    if (s == 0) {
        const float se  = sqrtf(fabsf(e));
        const float rfc = (l == 0) ? 1.0f : ((l == 1) ? (1.0f/3.0f) : (1.0f/15.0f));
        const float rt1 = (l == 0) ? (1.0f/3.0f) : ((l == 1) ? (1.0f/5.0f) : (1.0f/7.0f));
        const float rt2 = (l == 0) ? (1.0f/30.0f) : ((l == 1) ? (1.0f/70.0f) : (1.0f/126.0f));
        float pw[5];
        #pragma unroll
        for (int k = 0; k < 5; ++k) {
            float rinf = 99.6f + 0.1f * (float)k;
            float x  = rinf * se;
            float xl = (l == 0) ? 1.0f : ((l == 1) ? x : x * x);
            float h  = x * x * 0.5f;
            pw[k] = rinf * (xl * rfc * (1.0f + h * rt1 + (h * h) * rt2));
        }
        uinf[(size_t)899 * kNCH + t] = pw[4];
        float st0 = pw[1], st1 = pw[2], st2 = pw[3], st3 = pw[4];
        for (int ss = 0; ss < kSeg; ++ss) {
            if (ss < kSeg - 1) {
                float4 M0 = *(const float4*)&sM[ss][0][g][0];
                float4 M1 = *(const float4*)&sM[ss][1][g][0];
                float4 M2 = *(const float4*)&sM[ss][2][g][0];
                float4 M3 = *(const float4*)&sM[ss][3][g][0];
                *(float4*)&sM[ss][0][g][0] = make_float4(st0, st1, st2, st3);
                float n0 = fmaf(M0.w,st3, fmaf(M0.z,st2, fmaf(M0.y,st1, M0.x*st0)));
                float n1 = fmaf(M1.w,st3, fmaf(M1.z,st2, fmaf(M1.y,st1, M1.x*st0)));
                float n2 = fmaf(M2.w,st3, fmaf(M2.z,st2, fmaf(M2.y,st1, M2.x*st0)));
                float n3 = fmaf(M3.w,st3, fmaf(M3.z,st2, fmaf(M3.y,st1, M3.x*st0)));
                st0 = n0; st1 = n1; st2 = n2; st3 = n3;
            } else {
                *(float4*)&sM[ss][0][g][0] = make_float4(st0, st1, st2, st3);
            }
        }
    }
    __syncthreads();

    // ---- phase 3: uniform 28-step replay (s31: last 2 steps dummy) ----
    // slot K=0..3 <-> j === 1,2,3,0 mod 4: weights {acc2, 32u^4, 14u^4, 32u^4}
    float W0[4] = {0.0f, 32.0f, 14.0f, 32.0f};
    float V0[4] = {1.0f, 0.0f, 0.0f, 0.0f};
    float WR[4] = {0.0f, 32.0f, 14.0f, 32.0f};
    float VR[4] = {1.0f, 0.0f, 0.0f, 0.0f};
    if (s == 0) {   // rows 898,897 beyond integration; j=7 -> boundary weight 7
        W0[0]=0.0f; V0[0]=0.0f; W0[1]=0.0f; W0[2]=7.0f; W0[3]=32.0f;
    }

    F0 = ff0; F1 = ff1; F2 = ff2; F3 = ff3;
    float p0, p1, p2, p3;
    {
        float4 P = *(const float4*)&sM[s][0][g][0];
        p0 = P.x; p1 = P.y; p2 = P.z; p3 = P.w;
    }
    float acc4 = 0.0f, acc2 = 0.0f;
    float* ptr = uinf + (size_t)(903 - jstart) * kNCH + t;
#define RSTEPW(RI, FA,FB,FC,FD, PA,PB,PC,PD, W,V,K) \
    { COEF(RI, FA,FB,FC,FD) \
      float nw = fmaf(cd,PD, fmaf(cc_,PC, fmaf(cb,PB, ca*PA))); \
      PA = nw; *ptr = nw; ptr -= kNCH; \
      float v2 = nw*nw, v4 = v2*v2; \
      acc4 = fmaf(W[K], v4, acc4); \
      acc2 = fmaf(V[K], v2, acc2); }
#define PG(G, W, V) \
    { const float4 w = gq[G]; \
      RSTEPW(w.x, F0,F1,F2,F3, p0,p1,p2,p3, W,V,0) \
      RSTEPW(w.y, F1,F2,F3,F0, p1,p2,p3,p0, W,V,1) \
      RSTEPW(w.z, F2,F3,F0,F1, p2,p3,p0,p1, W,V,2) \
      RSTEPW(w.w, F3,F0,F1,F2, p3,p0,p1,p2, W,V,3) }

    PG(0, W0, V0)
    PG(1, WR, VR) PG(2, WR, VR) PG(3, WR, VR) PG(4, WR, VR) PG(5, WR, VR)
    // rotation restored: p0..p3 = w[jstart+20..jstart+23]
    float h0 = p1, h1 = p2, h2 = p3;
    if (s == 31) { WR[2] = 0.0f; WR[3] = 0.0f; }   // j=899,900 dummies
    PG(6, WR, VR)
    float h3 = p0, h4 = p1;
#undef PG
#undef RSTEPW

    {   // per-segment integral partials -> row-1 slots (matrices are dead)
        float2 rr; rr.x = acc4; rr.y = acc2;
        *(float2*)&sF[s * 256 + 64 + 4 * g] = rr;
    }
    __syncthreads();

    if (s == kSeg - 1) {
        float a4 = 0.0f, a2 = 0.0f;
        #pragma unroll
        for (int ss = 0; ss < kSeg; ++ss) {
            float2 rr = *(const float2*)&sF[ss * 256 + 64 + 4 * g];
            a4 += rr.x; a2 += rr.y;
        }
        // h0..h4 = w894..w898 -> u_infty rows 0..4
        uinf[(size_t)0 * kNCH + t] = h0;
        uinf[(size_t)1 * kNCH + t] = h1;
        uinf[(size_t)2 * kNCH + t] = h2;
        uinf[(size_t)3 * kNCH + t] = h3;
        uinf[(size_t)4 * kNCH + t] = h4;
        float q0 = h0*h0, q1 = h1*h1, q2 = h2*h2, q3 = h3*h3, q4 = h4*h4;
        a4 += 7.0f*q0*q0 + 32.0f*q1*q1 + 32.0f*q3*q3 + 14.0f*q4*q4;
        a2 += q2;
        float integ = fmaf(12.0f, a2, a4) * (2.0f * 0.1f / 45.0f);
        float deriv = fmaf(25.0f, h0, fmaf(-48.0f, h1, fmaf(36.0f, h2,
                      fmaf(-16.0f, h3, 3.0f * h4)))) * (1.0f / 1.2f);
        ws[t]        = deriv / h0;            // lfunc_out (pre energy-reversal)
        ws[kNCH + t] = integ / (h0 * h0);     // integ_out / u_infty[0]^2
    }
#undef MSTEP
#undef COEF
}

__global__ __launch_bounds__(256) void final_kernel(const float* __restrict__ energy,
                                                    const float* __restrict__ ws,
                                                    float* __restrict__ out)
{
    int t = (int)blockIdx.x * 256 + (int)threadIdx.x;
    if (t >= kNCH) return;
    int l = t % 3, ei = t / 3;
    float lf_out = ws[(kNE - 1 - ei) * 3 + l];   // energy-axis reversed
    float lf_in  = ws[2 * kNCH + t];
    float den    = ws[kNCH + t] + ws[3 * kNCH + t];
    out[t] = energy[ei] - (lf_out - lf_in) / den;
}

extern "C" void kernel_launch(void* const* d_in, const int* in_sizes, int n_in,
                              void* d_out, int out_size, void* d_ws, size_t ws_size,
                              hipStream_t stream) {
    (void)in_sizes; (void)n_in; (void)ws_size;
    const float* energy = (const float*)d_in[0];
    float* out = (float*)d_out;
    float* ws  = (float*)d_ws;   // 4*12288 floats = 192 KB (in-bounds)
    int n4 = out_size / 16;      // out_size divisible by 16 (12288*1001*4)
    warm_kernel<<<2048, 256, 0, stream>>>((float4*)out, n4);
    solve_kernel<<<kZeroBlocks + kInfBlocks, 512, 0, stream>>>(energy, out, ws);
    final_kernel<<<kNCH / 256, 256, 0, stream>>>(energy, ws, out);
}

// Round 10
// 88.959 us; speedup vs baseline: 1.3898x; 1.0025x over previous
//
#include <hip/hip_runtime.h>

// EvalEig round 17: 2 chains/thread ILP + float2 stores. r16 post-mortem:
// pre-touching all 49MB did NOT remove the penalty (solve still ~33 after
// warm) -> penalty is a drain conservation law, follows ANY write burst.
// Remaining lever: steady solve itself (21us = 2.3TB/s effective, well under
// the 6.3 ceiling; VALU issue ~4us, port ~8us). Never-isolated dimension:
// store transaction count (64B/wave) + zero ILP in the 4-deep FMA recurrence.
// This round: 32 chains x 32 segments per 512-thr block, each thread owns 2
// adjacent chains -> two independent recurrences (ILP-2, different l) and
// float2 stores (128B/wave-transaction, 344K transactions vs 688K).
// LDS 76KB -> 2 blocks/CU = 4 waves/SIMD (same as r10). u_zero unchanged.
// Predict steady 21->13-15, dur 84.9 -> 79-81; if null -> revert r12 and
// declare structural floor.

namespace {
constexpr int kNE    = 4096;
constexpr int kNCH   = kNE * 3;        // 12288 chains
constexpr int kMatch = 100;
constexpr float kC   = 3.0f / 40.0f * 0.01f;
constexpr float kK1  = 13.0f / 15.0f * 0.01f;
constexpr float kK2  = 7.0f / 60.0f * 0.01f;
constexpr int kSeg        = 32;           // segments per chain
constexpr int kPPB        = 16;           // chain-pairs per block (32 chains)
constexpr int kZeroBlocks = kNCH / 512;   // 24
constexpr int kInfBlocks  = kNCH / (2 * kPPB);  // 384
}

__device__ __forceinline__ float rcp_f(float x) { return __builtin_amdgcn_rcpf(x); }
__device__ __forceinline__ float rcp_nr(float x) {
    float r = __builtin_amdgcn_rcpf(x);
    return fmaf(fmaf(-x, r, 1.0f), r, r);
}

__global__ __launch_bounds__(512, 4) void solve_kernel(const float* __restrict__ energy,
                                                       float* __restrict__ out,
                                                       float* __restrict__ ws)
{
    // gtp[k] = 1/(100 - 0.1*(k-3)) for k in [4,901]; 1.0 dummies elsewhere.
    __shared__ __align__(16) float gtp[908];          // 3.6 KB
    __shared__ float sMA[kSeg][4][kPPB][4];           // 32 KB chain-A matrices
    __shared__ float sMB[kSeg][4][kPPB][4];           // 32 KB chain-B matrices
    __shared__ float4 sRed[kSeg][kPPB];               // 8 KB integral partials

    const int bid = (int)blockIdx.x;
    const int tid = (int)threadIdx.x;
    float* uzero = out + kNCH;
    float* uinf  = out + kNCH + (size_t)kMatch * kNCH;

    if (bid < kZeroBlocks) {
        // ---------------- u_zero: outward solve, 94 steps, 1 thread/chain ----
        const int t  = bid * 512 + tid;
        const int l  = t % 3;
        const int ei = t / 3;
        const float e = energy[ei], negE = -e;
        const float ll1 = (float)(l * (l + 1));
        const float rdiv = (l == 0) ? 0.5f : ((l == 1) ? 0.25f : (1.0f/6.0f));
        float p0,p1,p2,p3,p4;
        {
            float pw[5];
            #pragma unroll
            for (int k = 0; k < 5; ++k) {
                float r = 0.1f * (float)(k + 1);
                float rl1 = (l == 0) ? r : ((l == 1) ? r*r : r*r*r);
                pw[k] = rl1 - (rl1 * r) * rdiv;
                uzero[(size_t)k * kNCH + t] = pw[k];
            }
            uzero[(size_t)5 * kNCH + t] = pw[4];
            p0=pw[0]; p1=pw[1]; p2=pw[2]; p3=pw[3]; p4=pw[4];
        }
        float acc4, acc2;
        {
            float q0=p0*p0, q1=p1*p1, q2=p2*p2, q3=p3*p3, q4=p4*p4;
            acc4 = 7.0f*q0*q0 + 32.0f*q1*q1 + 32.0f*q3*q3 + 14.0f*q4*q4 + 32.0f*q4*q4;
            acc2 = q2;
        }
        float f0, f1, f2, f3;
        {
            float i1 = rcp_f(0.2f), i2 = rcp_f(0.3f), i3 = rcp_f(0.4f), i4 = rcp_f(0.5f);
            f0 = fmaf(i1, fmaf(ll1, i1, -1.0f), negE);
            f1 = fmaf(i2, fmaf(ll1, i2, -1.0f), negE);
            f2 = fmaf(i3, fmaf(ll1, i3, -1.0f), negE);
            f3 = fmaf(i4, fmaf(ll1, i4, -1.0f), negE);
        }
        float* ptr = uzero + (size_t)6 * kNCH + t;
        #pragma unroll 4
        for (int j = 5; j <= 98; ++j) {
            float ri = rcp_f(fmaf((float)j, 0.1f, 0.1f));
            float f4 = fmaf(ri, fmaf(ll1, ri, -1.0f), negE);
            float iv = rcp_f(fmaf(-kC, f4, 1.0f));
            float a  = fmaf(kC  * f0, iv, -1.0f);
            float b  = fmaf(kK1 * f1, iv,  2.0f);
            float cc = fmaf(kK2 * f2, iv, -2.0f);
            float d  = fmaf(kK1 * f3, iv,  2.0f);
            float nw = fmaf(d, p4, fmaf(cc, p3, fmaf(b, p2, a * p1)));
            *ptr = nw; ptr += kNCH;
            float v2 = nw*nw, v4 = v2*v2;
            if (j <= 94) {
                int m = (j + 1) & 3;
                if (m == 2)      acc2 += v2;
                else if (m == 0) acc4 += 14.0f * v4;
                else             acc4 += 32.0f * v4;
            } else if (j == 95) {
                acc4 += 7.0f * v4;
            }
            f0 = f1; f1 = f2; f2 = f3; f3 = f4;
            p0 = p1; p1 = p2; p2 = p3; p3 = p4; p4 = nw;
        }
        float integ = fmaf(12.0f, acc2, acc4) * (2.0f * 0.1f / 45.0f);
        float deriv = fmaf(25.0f, p4, fmaf(-48.0f, p3, fmaf(36.0f, p2,
                      fmaf(-16.0f, p1, 3.0f * p0)))) * (1.0f / 1.2f);
        ws[2 * kNCH + t] = deriv / p4;
        ws[3 * kNCH + t] = integ / (p4 * p4);
        return;
    }

    // ---------------- u_infty: 32-segment inward solve, 2 chains/thread ----
    for (int k = tid; k < 908; k += 512) {
        int j = k - 3;
        gtp[k] = (j >= 1 && j <= 898) ? rcp_nr(fmaf((float)j, -0.1f, 100.0f)) : 1.0f;
    }
    __syncthreads();

    const int b  = bid - kZeroBlocks;      // 0..383
    const int g  = tid & (kPPB - 1);       // pair index 0..15
    const int s  = tid >> 4;               // segment 0..31
    const int t2 = b * (2 * kPPB) + g * 2; // first chain of pair
    const int lA = t2 % 3,  lB = (t2 + 1) % 3;
    const float eA = energy[t2 / 3], eB = energy[(t2 + 1) / 3];
    const float negEA = -eA, negEB = -eB;
    const float ll1A = (float)(lA * (lA + 1));
    const float ll1B = (float)(lB * (lB + 1));
    const int jstart = 5 + 28 * s;         // uniform; s31 has 2 dummy steps

    const float4* gq = (const float4*)(&gtp[jstart + 3]);
    float fA0, fA1, fA2, fA3, fB0, fB1, fB2, fB3;
    {
        const float4 wF = *(const float4*)(&gtp[jstart - 1]);  // j-4..j-1
        fA0 = fmaf(wF.x, fmaf(ll1A, wF.x, -1.0f), negEA);
        fA1 = fmaf(wF.y, fmaf(ll1A, wF.y, -1.0f), negEA);
        fA2 = fmaf(wF.z, fmaf(ll1A, wF.z, -1.0f), negEA);
        fA3 = fmaf(wF.w, fmaf(ll1A, wF.w, -1.0f), negEA);
        fB0 = fmaf(wF.x, fmaf(ll1B, wF.x, -1.0f), negEB);
        fB1 = fmaf(wF.y, fmaf(ll1B, wF.y, -1.0f), negEB);
        fB2 = fmaf(wF.z, fmaf(ll1B, wF.z, -1.0f), negEB);
        fB3 = fmaf(wF.w, fmaf(ll1B, wF.w, -1.0f), negEB);
    }
    float FA0 = fA0, FA1 = fA1, FA2 = fA2, FA3 = fA3;
    float FB0 = fB0, FB1 = fB1, FB2 = fB2, FB3 = fB3;

    float caA, cbA, ccA, cdA, caB, cbB, ccB, cdB;
// dual-chain coefficient step: shared table value RI, per-chain everything else
#define COEF2(RI, A0,A1,A2,A3, B0,B1,B2,B3) \
    { float f4A = fmaf(RI, fmaf(ll1A, RI, -1.0f), negEA); \
      float f4B = fmaf(RI, fmaf(ll1B, RI, -1.0f), negEB); \
      float xA = kC * f4A, xB = kC * f4B; \
      float ivA = fmaf(xA, xA, xA) + 1.0f; \
      float ivB = fmaf(xB, xB, xB) + 1.0f; \
      caA = fmaf(kC  * A0, ivA, -1.0f);  caB = fmaf(kC  * B0, ivB, -1.0f); \
      cbA = fmaf(kK1 * A1, ivA,  2.0f);  cbB = fmaf(kK1 * B1, ivB,  2.0f); \
      ccA = fmaf(kK2 * A2, ivA, -2.0f);  ccB = fmaf(kK2 * B2, ivB, -2.0f); \
      cdA = fmaf(kK1 * A3, ivA,  2.0f);  cdB = fmaf(kK1 * B3, ivB,  2.0f); \
      A0 = f4A; B0 = f4B; }

#define MSTEP2(RI, A0,A1,A2,A3, B0,B1,B2,B3, RA,RB,RC,RD, QA,QB,QC,QD) \
    { COEF2(RI, A0,A1,A2,A3, B0,B1,B2,B3) \
      RA[0] = fmaf(cdA,RD[0], fmaf(ccA,RC[0], fmaf(cbA,RB[0], caA*RA[0]))); \
      QA[0] = fmaf(cdB,QD[0], fmaf(ccB,QC[0], fmaf(cbB,QB[0], caB*QA[0]))); \
      RA[1] = fmaf(cdA,RD[1], fmaf(ccA,RC[1], fmaf(cbA,RB[1], caA*RA[1]))); \
      QA[1] = fmaf(cdB,QD[1], fmaf(ccB,QC[1], fmaf(cbB,QB[1], caB*QA[1]))); \
      RA[2] = fmaf(cdA,RD[2], fmaf(ccA,RC[2], fmaf(cbA,RB[2], caA*RA[2]))); \
      QA[2] = fmaf(cdB,QD[2], fmaf(ccB,QC[2], fmaf(cbB,QB[2], caB*QA[2]))); \
      RA[3] = fmaf(cdA,RD[3], fmaf(ccA,RC[3], fmaf(cbA,RB[3], caA*RA[3]))); \
      QA[3] = fmaf(cdB,QD[3], fmaf(ccB,QC[3], fmaf(cbB,QB[3], caB*QA[3]))); }

    // ---- phase 1: companion products, uniform 28 steps for s<=30 ----
    if (s != 31) {
        float raA[4]={1,0,0,0}, rbA[4]={0,1,0,0}, rcA[4]={0,0,1,0}, rdA[4]={0,0,0,1};
        float raB[4]={1,0,0,0}, rbB[4]={0,1,0,0}, rcB[4]={0,0,1,0}, rdB[4]={0,0,0,1};
        #pragma unroll
        for (int gi = 0; gi < 7; ++gi) {
            const float4 w = gq[gi];
            MSTEP2(w.x, FA0,FA1,FA2,FA3, FB0,FB1,FB2,FB3, raA,rbA,rcA,rdA, raB,rbB,rcB,rdB)
            MSTEP2(w.y, FA1,FA2,FA3,FA0, FB1,FB2,FB3,FB0, rbA,rcA,rdA,raA, rbB,rcB,rdB,raB)
            MSTEP2(w.z, FA2,FA3,FA0,FA1, FB2,FB3,FB0,FB1, rcA,rdA,raA,rbA, rcB,rdB,raB,rbB)
            MSTEP2(w.w, FA3,FA0,FA1,FA2, FB3,FB0,FB1,FB2, rdA,raA,rbA,rcA, rdB,raB,rbB,rcB)
        }
        *(float4*)&sMA[s][0][g][0] = make_float4(raA[0], raA[1], raA[2], raA[3]);
        *(float4*)&sMA[s][1][g][0] = make_float4(rbA[0], rbA[1], rbA[2], rbA[3]);
        *(float4*)&sMA[s][2][g][0] = make_float4(rcA[0], rcA[1], rcA[2], rcA[3]);
        *(float4*)&sMA[s][3][g][0] = make_float4(rdA[0], rdA[1], rdA[2], rdA[3]);
        *(float4*)&sMB[s][0][g][0] = make_float4(raB[0], raB[1], raB[2], raB[3]);
        *(float4*)&sMB[s][1][g][0] = make_float4(rbB[0], rbB[1], rbB[2], rbB[3]);
        *(float4*)&sMB[s][2][g][0] = make_float4(rcB[0], rcB[1], rcB[2], rcB[3]);
        *(float4*)&sMB[s][3][g][0] = make_float4(rdB[0], rdB[1], rdB[2], rdB[3]);
    }
#undef MSTEP2
    __syncthreads();

    // ---- phase 2: per-pair serial combine (lanes tid 0..15, both chains).
    // Reads each segment's matrix rows, then overwrites row 0 with that
    // segment's start state (read-before-write makes the alias safe).
    if (s == 0) {
        float stA0, stA1, stA2, stA3, stB0, stB1, stB2, stB3;
        {
            const float seA = sqrtf(fabsf(eA)), seB = sqrtf(fabsf(eB));
            const float rfcA = (lA == 0) ? 1.0f : ((lA == 1) ? (1.0f/3.0f) : (1.0f/15.0f));
            const float rt1A = (lA == 0) ? (1.0f/3.0f) : ((lA == 1) ? (1.0f/5.0f) : (1.0f/7.0f));
            const float rt2A = (lA == 0) ? (1.0f/30.0f) : ((lA == 1) ? (1.0f/70.0f) : (1.0f/126.0f));
            const float rfcB = (lB == 0) ? 1.0f : ((lB == 1) ? (1.0f/3.0f) : (1.0f/15.0f));
            const float rt1B = (lB == 0) ? (1.0f/3.0f) : ((lB == 1) ? (1.0f/5.0f) : (1.0f/7.0f));
            const float rt2B = (lB == 0) ? (1.0f/30.0f) : ((lB == 1) ? (1.0f/70.0f) : (1.0f/126.0f));
            float pwA[5], pwB[5];
            #pragma unroll
            for (int k = 0; k < 5; ++k) {
                float rinf = 99.6f + 0.1f * (float)k;
                float xA = rinf * seA, xB = rinf * seB;
                float xlA = (lA == 0) ? 1.0f : ((lA == 1) ? xA : xA * xA);
                float xlB = (lB == 0) ? 1.0f : ((lB == 1) ? xB : xB * xB);
                float hA = xA * xA * 0.5f, hB = xB * xB * 0.5f;
                pwA[k] = rinf * (xlA * rfcA * (1.0f + hA * rt1A + (hA * hA) * rt2A));
                pwB[k] = rinf * (xlB * rfcB * (1.0f + hB * rt1B + (hB * hB) * rt2B));
            }
            *(float2*)&uinf[(size_t)899 * kNCH + t2] = make_float2(pwA[4], pwB[4]);
            stA0 = pwA[1]; stA1 = pwA[2]; stA2 = pwA[3]; stA3 = pwA[4];
            stB0 = pwB[1]; stB1 = pwB[2]; stB2 = pwB[3]; stB3 = pwB[4];
        }
        for (int ss = 0; ss < kSeg; ++ss) {
            if (ss < kSeg - 1) {
                float4 MA0 = *(const float4*)&sMA[ss][0][g][0];
                float4 MA1 = *(const float4*)&sMA[ss][1][g][0];
                float4 MA2 = *(const float4*)&sMA[ss][2][g][0];
                float4 MA3 = *(const float4*)&sMA[ss][3][g][0];
                float4 MB0 = *(const float4*)&sMB[ss][0][g][0];
                float4 MB1 = *(const float4*)&sMB[ss][1][g][0];
                float4 MB2 = *(const float4*)&sMB[ss][2][g][0];
                float4 MB3 = *(const float4*)&sMB[ss][3][g][0];
                *(float4*)&sMA[ss][0][g][0] = make_float4(stA0, stA1, stA2, stA3);
                *(float4*)&sMB[ss][0][g][0] = make_float4(stB0, stB1, stB2, stB3);
                float nA0 = fmaf(MA0.w,stA3, fmaf(MA0.z,stA2, fmaf(MA0.y,stA1, MA0.x*stA0)));
                float nA1 = fmaf(MA1.w,stA3, fmaf(MA1.z,stA2, fmaf(MA1.y,stA1, MA1.x*stA0)));
                float nA2 = fmaf(MA2.w,stA3, fmaf(MA2.z,stA2, fmaf(MA2.y,stA1, MA2.x*stA0)));
                float nA3 = fmaf(MA3.w,stA3, fmaf(MA3.z,stA2, fmaf(MA3.y,stA1, MA3.x*stA0)));
                float nB0 = fmaf(MB0.w,stB3, fmaf(MB0.z,stB2, fmaf(MB0.y,stB1, MB0.x*stB0)));
                float nB1 = fmaf(MB1.w,stB3, fmaf(MB1.z,stB2, fmaf(MB1.y,stB1, MB1.x*stB0)));
                float nB2 = fmaf(MB2.w,stB3, fmaf(MB2.z,stB2, fmaf(MB2.y,stB1, MB2.x*stB0)));
                float nB3 = fmaf(MB3.w,stB3, fmaf(MB3.z,stB2, fmaf(MB3.y,stB1, MB3.x*stB0)));
                stA0 = nA0; stA1 = nA1; stA2 = nA2; stA3 = nA3;
                stB0 = nB0; stB1 = nB1; stB2 = nB2; stB3 = nB3;
            } else {
                *(float4*)&sMA[ss][0][g][0] = make_float4(stA0, stA1, stA2, stA3);
                *(float4*)&sMB[ss][0][g][0] = make_float4(stB0, stB1, stB2, stB3);
            }
        }
    }
    __syncthreads();

    // ---- phase 3: uniform 28-step replay (s31: last 2 steps dummy) ----
    // slot K=0..3 <-> j === 1,2,3,0 mod 4: weights {acc2, 32u^4, 14u^4, 32u^4}
    float W0[4] = {0.0f, 32.0f, 14.0f, 32.0f};
    float V0[4] = {1.0f, 0.0f, 0.0f, 0.0f};
    float WR[4] = {0.0f, 32.0f, 14.0f, 32.0f};
    float VR[4] = {1.0f, 0.0f, 0.0f, 0.0f};
    if (s == 0) {   // rows 898,897 beyond integration; j=7 -> boundary weight 7
        W0[0]=0.0f; V0[0]=0.0f; W0[1]=0.0f; W0[2]=7.0f; W0[3]=32.0f;
    }

    FA0 = fA0; FA1 = fA1; FA2 = fA2; FA3 = fA3;
    FB0 = fB0; FB1 = fB1; FB2 = fB2; FB3 = fB3;
    float pA0, pA1, pA2, pA3, pB0, pB1, pB2, pB3;
    {
        float4 PA = *(const float4*)&sMA[s][0][g][0];
        float4 PB = *(const float4*)&sMB[s][0][g][0];
        pA0 = PA.x; pA1 = PA.y; pA2 = PA.z; pA3 = PA.w;
        pB0 = PB.x; pB1 = PB.y; pB2 = PB.z; pB3 = PB.w;
    }
    float acc4A = 0.0f, acc2A = 0.0f, acc4B = 0.0f, acc2B = 0.0f;
    float* ptr = uinf + (size_t)(903 - jstart) * kNCH + t2;
#define RSTEP2(RI, A0,A1,A2,A3, B0,B1,B2,B3, PA,PB,PC,PD, QA,QB,QC,QD, W,V,K) \
    { COEF2(RI, A0,A1,A2,A3, B0,B1,B2,B3) \
      float nwA = fmaf(cdA,PD, fmaf(ccA,PC, fmaf(cbA,PB, caA*PA))); \
      float nwB = fmaf(cdB,QD, fmaf(ccB,QC, fmaf(cbB,QB, caB*QA))); \
      PA = nwA; QA = nwB; \
      *(float2*)ptr = make_float2(nwA, nwB); ptr -= kNCH; \
      float v2A = nwA*nwA, v4A = v2A*v2A; \
      float v2B = nwB*nwB, v4B = v2B*v2B; \
      acc4A = fmaf(W[K], v4A, acc4A);  acc4B = fmaf(W[K], v4B, acc4B); \
      acc2A = fmaf(V[K], v2A, acc2A);  acc2B = fmaf(V[K], v2B, acc2B); }
#define PG(G, W, V) \
    { const float4 w = gq[G]; \
      RSTEP2(w.x, FA0,FA1,FA2,FA3, FB0,FB1,FB2,FB3, pA0,pA1,pA2,pA3, pB0,pB1,pB2,pB3, W,V,0) \
      RSTEP2(w.y, FA1,FA2,FA3,FA0, FB1,FB2,FB3,FB0, pA1,pA2,pA3,pA0, pB1,pB2,pB3,pB0, W,V,1) \
      RSTEP2(w.z, FA2,FA3,FA0,FA1, FB2,FB3,FB0,FB1, pA2,pA3,pA0,pA1, pB2,pB3,pB0,pB1, W,V,2) \
      RSTEP2(w.w, FA3,FA0,FA1,FA2, FB3,FB0,FB1,FB2, pA3,pA0,pA1,pA2, pB3,pB0,pB1,pB2, W,V,3) }

    PG(0, W0, V0)
    PG(1, WR, VR) PG(2, WR, VR) PG(3, WR, VR) PG(4, WR, VR) PG(5, WR, VR)
    // rotation restored: p0..p3 = w[jstart+20..jstart+23]
    float hA0 = pA1, hA1 = pA2, hA2 = pA3;
    float hB0 = pB1, hB1 = pB2, hB2 = pB3;
    if (s == 31) { WR[2] = 0.0f; WR[3] = 0.0f; }   // j=899,900 dummies
    PG(6, WR, VR)
    float hA3 = pA0, hA4 = pA1, hB3 = pB0, hB4 = pB1;
#undef PG
#undef RSTEP2
#undef COEF2

    sRed[s][g] = make_float4(acc4A, acc2A, acc4B, acc2B);
    __syncthreads();

    if (s == kSeg - 1) {
        float a4A = 0.0f, a2A = 0.0f, a4B = 0.0f, a2B = 0.0f;
        #pragma unroll
        for (int ss = 0; ss < kSeg; ++ss) {
            float4 rr = sRed[ss][g];
            a4A += rr.x; a2A += rr.y; a4B += rr.z; a2B += rr.w;
        }
        // h0..h4 = w894..w898 -> u_infty rows 0..4
        *(float2*)&uinf[(size_t)0 * kNCH + t2] = make_float2(hA0, hB0);
        *(float2*)&uinf[(size_t)1 * kNCH + t2] = make_float2(hA1, hB1);
        *(float2*)&uinf[(size_t)2 * kNCH + t2] = make_float2(hA2, hB2);
        *(float2*)&uinf[(size_t)3 * kNCH + t2] = make_float2(hA3, hB3);
        *(float2*)&uinf[(size_t)4 * kNCH + t2] = make_float2(hA4, hB4);
        float qA0=hA0*hA0, qA1=hA1*hA1, qA2=hA2*hA2, qA3=hA3*hA3, qA4=hA4*hA4;
        float qB0=hB0*hB0, qB1=hB1*hB1, qB2=hB2*hB2, qB3=hB3*hB3, qB4=hB4*hB4;
        a4A += 7.0f*qA0*qA0 + 32.0f*qA1*qA1 + 32.0f*qA3*qA3 + 14.0f*qA4*qA4;
        a4B += 7.0f*qB0*qB0 + 32.0f*qB1*qB1 + 32.0f*qB3*qB3 + 14.0f*qB4*qB4;
        a2A += qA2; a2B += qB2;
        float integA = fmaf(12.0f, a2A, a4A) * (2.0f * 0.1f / 45.0f);
        float integB = fmaf(12.0f, a2B, a4B) * (2.0f * 0.1f / 45.0f);
        float derivA = fmaf(25.0f, hA0, fmaf(-48.0f, hA1, fmaf(36.0f, hA2,
                       fmaf(-16.0f, hA3, 3.0f * hA4)))) * (1.0f / 1.2f);
        float derivB = fmaf(25.0f, hB0, fmaf(-48.0f, hB1, fmaf(36.0f, hB2,
                       fmaf(-16.0f, hB3, 3.0f * hB4)))) * (1.0f / 1.2f);
        ws[t2]            = derivA / hA0;
        ws[t2 + 1]        = derivB / hB0;
        ws[kNCH + t2]     = integA / (hA0 * hA0);
        ws[kNCH + t2 + 1] = integB / (hB0 * hB0);
    }
}

__global__ __launch_bounds__(256) void final_kernel(const float* __restrict__ energy,
                                                    const float* __restrict__ ws,
                                                    float* __restrict__ out)
{
    int t = (int)blockIdx.x * 256 + (int)threadIdx.x;
    if (t >= kNCH) return;
    int l = t % 3, ei = t / 3;
    float lf_out = ws[(kNE - 1 - ei) * 3 + l];   // energy-axis reversed
    float lf_in  = ws[2 * kNCH + t];
    float den    = ws[kNCH + t] + ws[3 * kNCH + t];
    out[t] = energy[ei] - (lf_out - lf_in) / den;
}

extern "C" void kernel_launch(void* const* d_in, const int* in_sizes, int n_in,
                              void* d_out, int out_size, void* d_ws, size_t ws_size,
                              hipStream_t stream) {
    (void)in_sizes; (void)n_in; (void)out_size; (void)ws_size;
    const float* energy = (const float*)d_in[0];
    float* out = (float*)d_out;
    float* ws  = (float*)d_ws;   // 4*12288 floats = 192 KB (in-bounds)
    solve_kernel<<<kZeroBlocks + kInfBlocks, 512, 0, stream>>>(energy, out, ws);
    final_kernel<<<kNCH / 256, 256, 0, stream>>>(energy, ws, out);
}

// Round 11
// 84.161 us; speedup vs baseline: 1.4690x; 1.0570x over previous
//
#include <hip/hip_runtime.h>

// EvalEig round 18: REVERT TO BEST (r12, measured 84.9us). Session ledger
// closes: dur = fill(45, harness poison @75% HBM peak, immovable) +
// solve(21 steady [r11 direct 3x-launch measurement] + ~16 conserved
// eviction/writeback work) + final(3) ~= 85. The ~16us excess is conserved
// memory traffic, proven by moving it between kernels (r13/r14 split, r16
// warm: totals unchanged) and by nulls on every store-path variant (NT r12,
// 64/128B width r7/r17, occupancy 4-7 waves r8, LDS batching r10, ILP-2
// r17). No remaining kernel-side lever with a surviving theory. This round
// re-locks the best configuration; expect ~85us.

namespace {
constexpr int kNE    = 4096;
constexpr int kNCH   = kNE * 3;        // 12288 chains
constexpr int kMatch = 100;
constexpr float kC   = 3.0f / 40.0f * 0.01f;
constexpr float kK1  = 13.0f / 15.0f * 0.01f;
constexpr float kK2  = 7.0f / 60.0f * 0.01f;
constexpr int kSeg        = 32;           // segments per chain
constexpr int kCPB        = 16;           // chains per block
constexpr int kZeroBlocks = kNCH / 512;   // 24
constexpr int kInfBlocks  = kNCH / kCPB;  // 768
}

__device__ __forceinline__ float rcp_f(float x) { return __builtin_amdgcn_rcpf(x); }
__device__ __forceinline__ float rcp_nr(float x) {
    float r = __builtin_amdgcn_rcpf(x);
    return fmaf(fmaf(-x, r, 1.0f), r, r);
}
__device__ __forceinline__ void nt_store(float* p, float v) {
    __builtin_nontemporal_store(v, p);
}

__global__ __launch_bounds__(512, 4) void solve_kernel(const float* __restrict__ energy,
                                                       float* __restrict__ out,
                                                       float* __restrict__ ws)
{
    // gtp[k] = 1/(100 - 0.1*(k-3)) for k in [4,901] (j = k-3 in [1,898]);
    // dummies = 1.0 elsewhere. +3 shift makes every group read 16B-aligned
    // (jstart === 1 mod 4  ->  padded base jstart+3 === 0 mod 4).
    __shared__ __align__(16) float gtp[908];  // 3.6 KB
    __shared__ float sM[kSeg][4][kCPB][4];    // 32 KB: [seg][matrix row][chain][col]
    float* sF = &sM[0][0][0][0];

    const int bid = (int)blockIdx.x;
    const int tid = (int)threadIdx.x;
    float* uzero = out + kNCH;
    float* uinf  = out + kNCH + (size_t)kMatch * kNCH;

    if (bid < kZeroBlocks) {
        // ---------------- u_zero: outward solve, 94 steps, 1 thread/chain ----
        const int t  = bid * 512 + tid;
        const int l  = t % 3;
        const int ei = t / 3;
        const float e = energy[ei], negE = -e;
        const float ll1 = (float)(l * (l + 1));
        const float rdiv = (l == 0) ? 0.5f : ((l == 1) ? 0.25f : (1.0f/6.0f));
        float p0,p1,p2,p3,p4;
        {
            float pw[5];
            #pragma unroll
            for (int k = 0; k < 5; ++k) {
                float r = 0.1f * (float)(k + 1);
                float rl1 = (l == 0) ? r : ((l == 1) ? r*r : r*r*r);
                pw[k] = rl1 - (rl1 * r) * rdiv;
                nt_store(&uzero[(size_t)k * kNCH + t], pw[k]);
            }
            nt_store(&uzero[(size_t)5 * kNCH + t], pw[4]);
            p0=pw[0]; p1=pw[1]; p2=pw[2]; p3=pw[3]; p4=pw[4];
        }
        float acc4, acc2;
        {
            float q0=p0*p0, q1=p1*p1, q2=p2*p2, q3=p3*p3, q4=p4*p4;
            acc4 = 7.0f*q0*q0 + 32.0f*q1*q1 + 32.0f*q3*q3 + 14.0f*q4*q4 + 32.0f*q4*q4;
            acc2 = q2;
        }
        float f0, f1, f2, f3;
        {
            float i1 = rcp_f(0.2f), i2 = rcp_f(0.3f), i3 = rcp_f(0.4f), i4 = rcp_f(0.5f);
            f0 = fmaf(i1, fmaf(ll1, i1, -1.0f), negE);
            f1 = fmaf(i2, fmaf(ll1, i2, -1.0f), negE);
            f2 = fmaf(i3, fmaf(ll1, i3, -1.0f), negE);
            f3 = fmaf(i4, fmaf(ll1, i4, -1.0f), negE);
        }
        float* ptr = uzero + (size_t)6 * kNCH + t;
        #pragma unroll 4
        for (int j = 5; j <= 98; ++j) {
            float ri = rcp_f(fmaf((float)j, 0.1f, 0.1f));
            float f4 = fmaf(ri, fmaf(ll1, ri, -1.0f), negE);
            float iv = rcp_f(fmaf(-kC, f4, 1.0f));
            float a  = fmaf(kC  * f0, iv, -1.0f);
            float b  = fmaf(kK1 * f1, iv,  2.0f);
            float cc = fmaf(kK2 * f2, iv, -2.0f);
            float d  = fmaf(kK1 * f3, iv,  2.0f);
            float nw = fmaf(d, p4, fmaf(cc, p3, fmaf(b, p2, a * p1)));
            nt_store(ptr, nw); ptr += kNCH;
            float v2 = nw*nw, v4 = v2*v2;
            if (j <= 94) {
                int m = (j + 1) & 3;
                if (m == 2)      acc2 += v2;
                else if (m == 0) acc4 += 14.0f * v4;
                else             acc4 += 32.0f * v4;
            } else if (j == 95) {
                acc4 += 7.0f * v4;
            }
            f0 = f1; f1 = f2; f2 = f3; f3 = f4;
            p0 = p1; p1 = p2; p2 = p3; p3 = p4; p4 = nw;
        }
        float integ = fmaf(12.0f, acc2, acc4) * (2.0f * 0.1f / 45.0f);
        float deriv = fmaf(25.0f, p4, fmaf(-48.0f, p3, fmaf(36.0f, p2,
                      fmaf(-16.0f, p1, 3.0f * p0)))) * (1.0f / 1.2f);
        ws[2 * kNCH + t] = deriv / p4;
        ws[3 * kNCH + t] = integ / (p4 * p4);
        return;
    }

    // ---------------- u_infty: 32-segment inward solve ----------------
    for (int k = tid; k < 908; k += 512) {
        int j = k - 3;
        gtp[k] = (j >= 1 && j <= 898) ? rcp_nr(fmaf((float)j, -0.1f, 100.0f)) : 1.0f;
    }
    __syncthreads();

    const int b = bid - kZeroBlocks;
    const int g = tid & (kCPB - 1);        // chain within block
    const int s = tid >> 4;                // segment 0..31 (4 per wave)
    const int t = b * kCPB + g;
    const int l  = t % 3;
    const int ei = t / 3;
    const float e = energy[ei], negE = -e;
    const float ll1 = (float)(l * (l + 1));
    // uniform: seg s covers j = jstart .. jstart+27 (s31: last 2 are dummies)
    const int jstart = 5 + 28 * s;

    const float4* gq = (const float4*)(&gtp[jstart + 3]);   // group G = j jstart+4G..+3
    float ff0, ff1, ff2, ff3;
    {
        const float4 wF = *(const float4*)(&gtp[jstart - 1]);  // j-4..j-1
        ff0 = fmaf(wF.x, fmaf(ll1, wF.x, -1.0f), negE);
        ff1 = fmaf(wF.y, fmaf(ll1, wF.y, -1.0f), negE);
        ff2 = fmaf(wF.z, fmaf(ll1, wF.z, -1.0f), negE);
        ff3 = fmaf(wF.w, fmaf(ll1, wF.w, -1.0f), negE);
    }
    float F0 = ff0, F1 = ff1, F2 = ff2, F3 = ff3;

    float ca, cb, cc_, cd;
#define COEF(RI, FA,FB,FC,FD) \
    { float f4 = fmaf(RI, fmaf(ll1, RI, -1.0f), negE); \
      float x  = kC * f4; \
      float iv = fmaf(x, x, x) + 1.0f; \
      ca  = fmaf(kC  * FA, iv, -1.0f); \
      cb  = fmaf(kK1 * FB, iv,  2.0f); \
      cc_ = fmaf(kK2 * FC, iv, -2.0f); \
      cd  = fmaf(kK1 * FD, iv,  2.0f); \
      FA = f4; }

#define MSTEP(RI, FA,FB,FC,FD, RA,RB,RC,RD) \
    { COEF(RI, FA,FB,FC,FD) \
      RA[0] = fmaf(cd,RD[0], fmaf(cc_,RC[0], fmaf(cb,RB[0], ca*RA[0]))); \
      RA[1] = fmaf(cd,RD[1], fmaf(cc_,RC[1], fmaf(cb,RB[1], ca*RA[1]))); \
      RA[2] = fmaf(cd,RD[2], fmaf(cc_,RC[2], fmaf(cb,RB[2], ca*RA[2]))); \
      RA[3] = fmaf(cd,RD[3], fmaf(cc_,RC[3], fmaf(cb,RB[3], ca*RA[3]))); }

    // ---- phase 1: companion products, uniform 28 steps for s<=30 ----
    if (s != 31) {
        float ra[4] = {1,0,0,0}, rb[4] = {0,1,0,0}, rc[4] = {0,0,1,0}, rd[4] = {0,0,0,1};
        #pragma unroll
        for (int gi = 0; gi < 7; ++gi) {
            const float4 w = gq[gi];
            MSTEP(w.x, F0,F1,F2,F3, ra,rb,rc,rd)
            MSTEP(w.y, F1,F2,F3,F0, rb,rc,rd,ra)
            MSTEP(w.z, F2,F3,F0,F1, rc,rd,ra,rb)
            MSTEP(w.w, F3,F0,F1,F2, rd,ra,rb,rc)
        }
        *(float4*)&sM[s][0][g][0] = make_float4(ra[0], ra[1], ra[2], ra[3]);
        *(float4*)&sM[s][1][g][0] = make_float4(rb[0], rb[1], rb[2], rb[3]);
        *(float4*)&sM[s][2][g][0] = make_float4(rc[0], rc[1], rc[2], rc[3]);
        *(float4*)&sM[s][3][g][0] = make_float4(rd[0], rd[1], rd[2], rd[3]);
    }
    __syncthreads();

    // ---- phase 2: per-chain serial combine (lanes tid 0..15). Reads each
    // segment's matrix rows, then overwrites row 0 with that segment's start
    // state (read-before-write makes the alias safe).
    if (s == 0) {
        const float se  = sqrtf(fabsf(e));
        const float rfc = (l == 0) ? 1.0f : ((l == 1) ? (1.0f/3.0f) : (1.0f/15.0f));
        const float rt1 = (l == 0) ? (1.0f/3.0f) : ((l == 1) ? (1.0f/5.0f) : (1.0f/7.0f));
        const float rt2 = (l == 0) ? (1.0f/30.0f) : ((l == 1) ? (1.0f/70.0f) : (1.0f/126.0f));
        float pw[5];
        #pragma unroll
        for (int k = 0; k < 5; ++k) {
            float rinf = 99.6f + 0.1f * (float)k;
            float x  = rinf * se;
            float xl = (l == 0) ? 1.0f : ((l == 1) ? x : x * x);
            float h  = x * x * 0.5f;
            pw[k] = rinf * (xl * rfc * (1.0f + h * rt1 + (h * h) * rt2));
        }
        nt_store(&uinf[(size_t)899 * kNCH + t], pw[4]);
        float st0 = pw[1], st1 = pw[2], st2 = pw[3], st3 = pw[4];
        for (int ss = 0; ss < kSeg; ++ss) {
            if (ss < kSeg - 1) {
                float4 M0 = *(const float4*)&sM[ss][0][g][0];
                float4 M1 = *(const float4*)&sM[ss][1][g][0];
                float4 M2 = *(const float4*)&sM[ss][2][g][0];
                float4 M3 = *(const float4*)&sM[ss][3][g][0];
                *(float4*)&sM[ss][0][g][0] = make_float4(st0, st1, st2, st3);
                float n0 = fmaf(M0.w,st3, fmaf(M0.z,st2, fmaf(M0.y,st1, M0.x*st0)));
                float n1 = fmaf(M1.w,st3, fmaf(M1.z,st2, fmaf(M1.y,st1, M1.x*st0)));
                float n2 = fmaf(M2.w,st3, fmaf(M2.z,st2, fmaf(M2.y,st1, M2.x*st0)));
                float n3 = fmaf(M3.w,st3, fmaf(M3.z,st2, fmaf(M3.y,st1, M3.x*st0)));
                st0 = n0; st1 = n1; st2 = n2; st3 = n3;
            } else {
                *(float4*)&sM[ss][0][g][0] = make_float4(st0, st1, st2, st3);
            }
        }
    }
    __syncthreads();

    // ---- phase 3: uniform 28-step replay (s31: last 2 steps dummy) ----
    // slot K=0..3 <-> j === 1,2,3,0 mod 4: weights {acc2, 32u^4, 14u^4, 32u^4}
    float W0[4] = {0.0f, 32.0f, 14.0f, 32.0f};
    float V0[4] = {1.0f, 0.0f, 0.0f, 0.0f};
    float WR[4] = {0.0f, 32.0f, 14.0f, 32.0f};
    float VR[4] = {1.0f, 0.0f, 0.0f, 0.0f};
    if (s == 0) {   // rows 898,897 beyond integration; j=7 -> boundary weight 7
        W0[0]=0.0f; V0[0]=0.0f; W0[1]=0.0f; W0[2]=7.0f; W0[3]=32.0f;
    }

    F0 = ff0; F1 = ff1; F2 = ff2; F3 = ff3;
    float p0, p1, p2, p3;
    {
        float4 P = *(const float4*)&sM[s][0][g][0];
        p0 = P.x; p1 = P.y; p2 = P.z; p3 = P.w;
    }
    float acc4 = 0.0f, acc2 = 0.0f;
    float* ptr = uinf + (size_t)(903 - jstart) * kNCH + t;
#define RSTEPW(RI, FA,FB,FC,FD, PA,PB,PC,PD, W,V,K) \
    { COEF(RI, FA,FB,FC,FD) \
      float nw = fmaf(cd,PD, fmaf(cc_,PC, fmaf(cb,PB, ca*PA))); \
      PA = nw; nt_store(ptr, nw); ptr -= kNCH; \
      float v2 = nw*nw, v4 = v2*v2; \
      acc4 = fmaf(W[K], v4, acc4); \
      acc2 = fmaf(V[K], v2, acc2); }
#define PG(G, W, V) \
    { const float4 w = gq[G]; \
      RSTEPW(w.x, F0,F1,F2,F3, p0,p1,p2,p3, W,V,0) \
      RSTEPW(w.y, F1,F2,F3,F0, p1,p2,p3,p0, W,V,1) \
      RSTEPW(w.z, F2,F3,F0,F1, p2,p3,p0,p1, W,V,2) \
      RSTEPW(w.w, F3,F0,F1,F2, p3,p0,p1,p2, W,V,3) }

    PG(0, W0, V0)
    PG(1, WR, VR) PG(2, WR, VR) PG(3, WR, VR) PG(4, WR, VR) PG(5, WR, VR)
    // rotation restored: p0..p3 = w[jstart+20..jstart+23]
    float h0 = p1, h1 = p2, h2 = p3;
    if (s == 31) { WR[2] = 0.0f; WR[3] = 0.0f; }   // j=899,900 dummies
    PG(6, WR, VR)
    float h3 = p0, h4 = p1;
#undef PG
#undef RSTEPW

    {   // per-segment integral partials -> row-1 slots (matrices are dead)
        float2 rr; rr.x = acc4; rr.y = acc2;
        *(float2*)&sF[s * 256 + 64 + 4 * g] = rr;
    }
    __syncthreads();

    if (s == kSeg - 1) {
        float a4 = 0.0f, a2 = 0.0f;
        #pragma unroll
        for (int ss = 0; ss < kSeg; ++ss) {
            float2 rr = *(const float2*)&sF[ss * 256 + 64 + 4 * g];
            a4 += rr.x; a2 += rr.y;
        }
        // h0..h4 = w894..w898 -> u_infty rows 0..4
        nt_store(&uinf[(size_t)0 * kNCH + t], h0);
        nt_store(&uinf[(size_t)1 * kNCH + t], h1);
        nt_store(&uinf[(size_t)2 * kNCH + t], h2);
        nt_store(&uinf[(size_t)3 * kNCH + t], h3);
        nt_store(&uinf[(size_t)4 * kNCH + t], h4);
        float q0 = h0*h0, q1 = h1*h1, q2 = h2*h2, q3 = h3*h3, q4 = h4*h4;
        a4 += 7.0f*q0*q0 + 32.0f*q1*q1 + 32.0f*q3*q3 + 14.0f*q4*q4;
        a2 += q2;
        float integ = fmaf(12.0f, a2, a4) * (2.0f * 0.1f / 45.0f);
        float deriv = fmaf(25.0f, h0, fmaf(-48.0f, h1, fmaf(36.0f, h2,
                      fmaf(-16.0f, h3, 3.0f * h4)))) * (1.0f / 1.2f);
        ws[t]        = deriv / h0;            // lfunc_out (pre energy-reversal)
        ws[kNCH + t] = integ / (h0 * h0);     // integ_out / u_infty[0]^2
    }
#undef MSTEP
#undef COEF
}

__global__ __launch_bounds__(256) void final_kernel(const float* __restrict__ energy,
                                                    const float* __restrict__ ws,
                                                    float* __restrict__ out)
{
    int t = (int)blockIdx.x * 256 + (int)threadIdx.x;
    if (t >= kNCH) return;
    int l = t % 3, ei = t / 3;
    float lf_out = ws[(kNE - 1 - ei) * 3 + l];   // energy-axis reversed
    float lf_in  = ws[2 * kNCH + t];
    float den    = ws[kNCH + t] + ws[3 * kNCH + t];
    nt_store(&out[t], energy[ei] - (lf_out - lf_in) / den);
}

extern "C" void kernel_launch(void* const* d_in, const int* in_sizes, int n_in,
                              void* d_out, int out_size, void* d_ws, size_t ws_size,
                              hipStream_t stream) {
    (void)in_sizes; (void)n_in; (void)out_size; (void)ws_size;
    const float* energy = (const float*)d_in[0];
    float* out = (float*)d_out;
    float* ws  = (float*)d_ws;   // 4*12288 floats = 192 KB (in-bounds)
    solve_kernel<<<kZeroBlocks + kInfBlocks, 512, 0, stream>>>(energy, out, ws);
    final_kernel<<<kNCH / 256, 256, 0, stream>>>(energy, ws, out);
}